// Round 4
// baseline (108.111 us; speedup 1.0000x reference)
//
#include <hip/hip_runtime.h>

#define BN 2
#define T_DIM 2048
#define D_DIM 1024
#define H_N 16
#define DH_N 64
#define WIN 256
#define NROWS (BN * T_DIM)   // 4096
#define KDIM 1024            // inner dim for all GEMMs

typedef __attribute__((ext_vector_type(8))) short bf16x8;
typedef __attribute__((ext_vector_type(4))) float f32x4;
typedef __attribute__((ext_vector_type(8))) unsigned short ushort8;
typedef __attribute__((ext_vector_type(4))) unsigned short u16x4;

static __device__ __forceinline__ unsigned short f2bf(float f) {
  unsigned int u = __float_as_uint(f);
  unsigned int r = (u + 0x7FFFu + ((u >> 16) & 1u)) >> 16;  // RNE
  return (unsigned short)r;
}

static __device__ __forceinline__ void gl_lds16(const void* g, void* l) {
  __builtin_amdgcn_global_load_lds(
      (const __attribute__((address_space(1))) unsigned int*)g,
      (__attribute__((address_space(3))) unsigned int*)l, 16, 0, 0);
}

// ---------------------------------------------------------------------------
// f32 -> bf16 elementwise (8 elems/thread)
// ---------------------------------------------------------------------------
__global__ __launch_bounds__(256) void convert_bf(const float* __restrict__ src,
                                                  unsigned short* __restrict__ dst) {
  int i = (blockIdx.x * 256 + threadIdx.x) * 8;
  float4 a = *(const float4*)(src + i);
  float4 b = *(const float4*)(src + i + 4);
  ushort8 o;
  o[0] = f2bf(a.x); o[1] = f2bf(a.y); o[2] = f2bf(a.z); o[3] = f2bf(a.w);
  o[4] = f2bf(b.x); o[5] = f2bf(b.y); o[6] = f2bf(b.z); o[7] = f2bf(b.w);
  *(ushort8*)(dst + i) = o;
}

// ---------------------------------------------------------------------------
// f32 [R][C] -> bf16 [C][R] tiled transpose (64x64 tiles)
// ---------------------------------------------------------------------------
__global__ __launch_bounds__(256) void convert_t(const float* __restrict__ src,
                                                 unsigned short* __restrict__ dst,
                                                 int R, int C) {
  __shared__ float tile[64][65];
  const int t = threadIdx.x;
  const int bc = blockIdx.x * 64, br = blockIdx.y * 64;
#pragma unroll
  for (int i = 0; i < 16; ++i) {
    int idx = i * 256 + t;
    int r = idx >> 6, c = idx & 63;
    tile[r][c] = src[(size_t)(br + r) * C + bc + c];
  }
  __syncthreads();
#pragma unroll
  for (int i = 0; i < 16; ++i) {
    int idx = i * 256 + t;
    int r = idx >> 6, c = idx & 63;
    dst[(size_t)(bc + r) * R + br + c] = f2bf(tile[c][r]);
  }
}

// ---------------------------------------------------------------------------
// NEW: 256x256-tile qkv GEMM. 8 waves (2M x 4N), BK=32, double-buffered
// 64KB LDS, lead-1 prefetch with raw s_barrier + inline-asm vmcnt(0) only,
// T2 swizzle (slot ^ row&3) via pre-swizzled global src, T1 XCD swizzle,
// T5 setprio. A [4096][1024] bf16, Bt [3072][1024] bf16.
// Epilogue scatters q,k bf16 [B,H,T,64] (q*0.125) and v^T bf16 [B,H,64,T].
// ---------------------------------------------------------------------------
__global__ __launch_bounds__(512) void gemm256_qkv(
    const unsigned short* __restrict__ A, const unsigned short* __restrict__ Bt,
    const float* __restrict__ bias, unsigned short* __restrict__ qo,
    unsigned short* __restrict__ ko, unsigned short* __restrict__ vto) {
  __shared__ unsigned short As[2][8192];  // [buf][256 rows * 32 k] = 16KB each
  __shared__ unsigned short Bs[2][8192];

  const int tid = threadIdx.x;
  const int w = tid >> 6, l = tid & 63;
  const int wr = w >> 2, wc = w & 3;  // 2M x 4N waves; per-wave out 128x64

  // T1: bijective XCD swizzle (nwg=192, q=24, r=0)
  const int id = blockIdx.x;
  const int wg = (id & 7) * 24 + (id >> 3);
  const int bx = wg % 12, by = wg / 12;
  const int r0 = by * 256, c0 = bx * 256;

  const unsigned short* Ag = A + (size_t)r0 * KDIM;
  const unsigned short* Bg = Bt + (size_t)c0 * KDIM;

  f32x4 acc[8][4];
#pragma unroll
  for (int i = 0; i < 8; ++i)
#pragma unroll
    for (int j = 0; j < 4; ++j) acc[i][j] = (f32x4){0.f, 0.f, 0.f, 0.f};

  // staging geometry: slot = 16B (8 bf16) of one row; row has 4 slots (BK=32)
  const int srow_lo = l >> 2;                       // 0..15 within 16-row chunk
  const int srcslot = (l & 3) ^ ((l >> 2) & 3);     // T2 swizzle on global src

#define STAGE(kt, bsel)                                                        \
  do {                                                                         \
    const int k0_ = (kt) * 32;                                                 \
    _Pragma("unroll") for (int i_ = 0; i_ < 2; ++i_) {                         \
      int sb_ = i_ * 8 + w; /* 16-row chunk, wave-uniform */                   \
      int row_ = sb_ * 16 + srow_lo;                                           \
      gl_lds16(Ag + (size_t)row_ * KDIM + k0_ + srcslot * 8,                   \
               (char*)&As[bsel][0] + sb_ * 1024);                              \
      gl_lds16(Bg + (size_t)row_ * KDIM + k0_ + srcslot * 8,                   \
               (char*)&Bs[bsel][0] + sb_ * 1024);                              \
    }                                                                          \
  } while (0)

  // fragment read offsets (swizzled): byte = row*64 + ((l>>4 ^ row&3)<<4)
  const int kslc = l >> 4;

  STAGE(0, 0);
  asm volatile("s_waitcnt vmcnt(0)" ::: "memory");
  __builtin_amdgcn_s_barrier();

  for (int t = 0; t < 32; ++t) {
    const int cb = t & 1, nb = cb ^ 1;
    if (t + 1 < 32) STAGE(t + 1, nb);

    bf16x8 a[4], b[4];
    // phase 0: m0-3 x n0-3
#pragma unroll
    for (int mi = 0; mi < 4; ++mi) {
      int row = wr * 128 + mi * 16 + (l & 15);
      a[mi] = *(const bf16x8*)((const char*)&As[cb][0] + row * 64 +
                               ((kslc ^ (row & 3)) << 4));
    }
#pragma unroll
    for (int ni = 0; ni < 4; ++ni) {
      int row = wc * 64 + ni * 16 + (l & 15);
      b[ni] = *(const bf16x8*)((const char*)&Bs[cb][0] + row * 64 +
                               ((kslc ^ (row & 3)) << 4));
    }
    __builtin_amdgcn_s_setprio(1);
#pragma unroll
    for (int mi = 0; mi < 4; ++mi)
#pragma unroll
      for (int ni = 0; ni < 4; ++ni)
        acc[mi][ni] = __builtin_amdgcn_mfma_f32_16x16x32_bf16(a[mi], b[ni],
                                                              acc[mi][ni], 0, 0, 0);
    __builtin_amdgcn_s_setprio(0);
    // phase 1: m4-7 x n0-3 (b reused)
#pragma unroll
    for (int mi = 0; mi < 4; ++mi) {
      int row = wr * 128 + (mi + 4) * 16 + (l & 15);
      a[mi] = *(const bf16x8*)((const char*)&As[cb][0] + row * 64 +
                               ((kslc ^ (row & 3)) << 4));
    }
    __builtin_amdgcn_s_setprio(1);
#pragma unroll
    for (int mi = 0; mi < 4; ++mi)
#pragma unroll
      for (int ni = 0; ni < 4; ++ni)
        acc[mi + 4][ni] = __builtin_amdgcn_mfma_f32_16x16x32_bf16(
            a[mi], b[ni], acc[mi + 4][ni], 0, 0, 0);
    __builtin_amdgcn_s_setprio(0);

    if (t + 1 < 32) asm volatile("s_waitcnt vmcnt(0)" ::: "memory");
    __builtin_amdgcn_s_barrier();
  }
#undef STAGE

  // epilogue: which/h uniform per block/wave (c0 256-aligned, 256 | 1024)
  const int which = (c0 + wc * 64) >> 10;  // 0=q,1=k,2=v
  const int h = ((c0 + wc * 64) >> 6) & 15;
#pragma unroll
  for (int mi = 0; mi < 8; ++mi) {
#pragma unroll
    for (int ni = 0; ni < 4; ++ni) {
      int row = r0 + wr * 128 + mi * 16 + (l >> 4) * 4;  // multiple of 4
      int dh = ni * 16 + (l & 15);
      float bv = bias[c0 + wc * 64 + dh];
      int b_ = row >> 11, t0 = row & 2047;
      if (which == 2) {
        u16x4 pk;
#pragma unroll
        for (int j = 0; j < 4; ++j) pk[j] = f2bf(acc[mi][ni][j] + bv);
        *(u16x4*)(vto + ((size_t)(b_ * H_N + h) * DH_N + dh) * T_DIM + t0) = pk;
      } else {
        float mul = (which == 0) ? 0.125f : 1.0f;
        unsigned short* dst = (which == 0) ? qo : ko;
#pragma unroll
        for (int j = 0; j < 4; ++j)
          dst[((size_t)(b_ * H_N + h) * T_DIM + t0 + j) * DH_N + dh] =
              f2bf((acc[mi][ni][j] + bv) * mul);
      }
    }
  }
}

// ---------------------------------------------------------------------------
// out-proj GEMM (m97 structure, unchanged): 128x128 tile, BK=32, 4 waves.
// C = A@B + bias -> float out [M][1024]
// ---------------------------------------------------------------------------
__global__ __launch_bounds__(256) void mfma_gemm_out(
    const unsigned short* __restrict__ A, const unsigned short* __restrict__ Bt,
    const float* __restrict__ bias, float* __restrict__ fo) {
  __shared__ unsigned short As[128 * 32];
  __shared__ unsigned short Bs[128 * 32];
  const int tid = threadIdx.x;
  const int w = tid >> 6, l = tid & 63;
  const int wr = w >> 1, wc = w & 1;
  const int r0 = blockIdx.y * 128, c0 = blockIdx.x * 128;

  f32x4 acc[4][4];
#pragma unroll
  for (int i = 0; i < 4; ++i)
#pragma unroll
    for (int j = 0; j < 4; ++j) acc[i][j] = (f32x4){0.f, 0.f, 0.f, 0.f};

  const unsigned short* Ag = A + (size_t)r0 * KDIM;
  const unsigned short* Bg = Bt + (size_t)c0 * KDIM;
  const int srow = l >> 2;
  const int skoff = (l & 3) * 8;

  for (int k0 = 0; k0 < KDIM; k0 += 32) {
#pragma unroll
    for (int i = 0; i < 2; ++i) {
      int chunk = i * 4 + w;
      int mrow = chunk * 16 + srow;
      gl_lds16(Ag + (size_t)mrow * KDIM + k0 + skoff, (char*)As + chunk * 1024);
      gl_lds16(Bg + (size_t)mrow * KDIM + k0 + skoff, (char*)Bs + chunk * 1024);
    }
    __syncthreads();

    bf16x8 a[4], b[4];
#pragma unroll
    for (int mi = 0; mi < 4; ++mi)
      a[mi] = *(const bf16x8*)((const char*)As +
                               (wr * 64 + mi * 16 + (l & 15)) * 64 + (l >> 4) * 16);
#pragma unroll
    for (int ni = 0; ni < 4; ++ni)
      b[ni] = *(const bf16x8*)((const char*)Bs +
                               (wc * 64 + ni * 16 + (l & 15)) * 64 + (l >> 4) * 16);
#pragma unroll
    for (int mi = 0; mi < 4; ++mi)
#pragma unroll
      for (int ni = 0; ni < 4; ++ni)
        acc[mi][ni] = __builtin_amdgcn_mfma_f32_16x16x32_bf16(a[mi], b[ni],
                                                              acc[mi][ni], 0, 0, 0);
    __syncthreads();
  }

#pragma unroll
  for (int mi = 0; mi < 4; ++mi) {
#pragma unroll
    for (int ni = 0; ni < 4; ++ni) {
      int row = r0 + wr * 64 + mi * 16 + (l >> 4) * 4;
      int col = c0 + wc * 64 + ni * 16 + (l & 15);
      float bv = bias[col];
#pragma unroll
      for (int j = 0; j < 4; ++j)
        fo[(size_t)(row + j) * D_DIM + col] = acc[mi][ni][j] + bv;
    }
  }
}

// ---------------------------------------------------------------------------
// MFMA windowed flash attention (unchanged from round 3).
// ---------------------------------------------------------------------------
__global__ __launch_bounds__(256) void attn_mfma(
    const unsigned short* __restrict__ qbf,
    const unsigned short* __restrict__ kbf,
    const unsigned short* __restrict__ vtbf,
    unsigned short* __restrict__ ctx) {
  __shared__ unsigned short Ks[64 * 64];
  __shared__ unsigned short Vs[64 * 64];
  const int tid = threadIdx.x;
  const int w = tid >> 6, l = tid & 63;
  const int g = l >> 4, ln = l & 15;
  const int qt = blockIdx.x & 31;
  const int bh = blockIdx.x >> 5;
  const int q0 = qt * 64;
  const int q_abs = q0 + w * 16 + ln;

  const unsigned short* kp = kbf + (size_t)bh * T_DIM * DH_N;
  const unsigned short* vtp = vtbf + (size_t)bh * DH_N * T_DIM;

  bf16x8 qf0, qf1;
  {
    const unsigned short* qp = qbf + ((size_t)bh * T_DIM + q_abs) * DH_N;
    qf0 = *(const bf16x8*)(qp + g * 8);
    qf1 = *(const bf16x8*)(qp + 32 + g * 8);
  }

  f32x4 acc_o[4];
#pragma unroll
  for (int nd = 0; nd < 4; ++nd) acc_o[nd] = (f32x4){0.f, 0.f, 0.f, 0.f};
  float m = -1e30f, lsum = 0.f;

  const int kt_lo = (q0 >= WIN) ? (q0 - WIN) : 0;
  for (int kt = kt_lo; kt <= q0; kt += 64) {
    __syncthreads();
#pragma unroll
    for (int i = 0; i < 2; ++i) {
      int chunk = i * 256 + tid;
      int row = chunk >> 3, c16 = chunk & 7;
      int sc16 = c16 ^ (row & 7);
      int kap = 32 * ((row >> 4) & 1) + 8 * ((row & 15) >> 2) + 4 * (row >> 5) +
                (row & 3);
      gl_lds16(kp + (size_t)(kt + kap) * DH_N + sc16 * 8, (char*)Ks + chunk * 16);
      gl_lds16(vtp + (size_t)row * T_DIM + kt + sc16 * 8, (char*)Vs + chunk * 16);
    }
    __syncthreads();

    f32x4 sacc[4];
#pragma unroll
    for (int nk = 0; nk < 4; ++nk) sacc[nk] = (f32x4){0.f, 0.f, 0.f, 0.f};
#pragma unroll
    for (int ks = 0; ks < 2; ++ks) {
      bf16x8 qf = ks ? qf1 : qf0;
#pragma unroll
      for (int nk = 0; nk < 4; ++nk) {
        int rrow = nk * 16 + ln;
        int c16 = ks * 4 + g;
        bf16x8 kf = *(const bf16x8*)((const char*)Ks + rrow * 128 +
                                     ((c16 ^ (rrow & 7)) * 16));
        sacc[nk] = __builtin_amdgcn_mfma_f32_16x16x32_bf16(kf, qf, sacc[nk], 0, 0, 0);
      }
    }

    float p[4][4];
    float tm = -1e30f;
#pragma unroll
    for (int nk = 0; nk < 4; ++nk)
#pragma unroll
      for (int j = 0; j < 4; ++j) {
        int k_abs = kt + 32 * (nk & 1) + 8 * g + 4 * (nk >> 1) + j;
        float s = sacc[nk][j];
        bool ok = (k_abs <= q_abs) && (k_abs + WIN >= q_abs);
        s = ok ? s : -1e30f;
        p[nk][j] = s;
        tm = fmaxf(tm, s);
      }
    tm = fmaxf(tm, __shfl_xor(tm, 16, 64));
    tm = fmaxf(tm, __shfl_xor(tm, 32, 64));
    float mn = fmaxf(m, tm);
    float sc = __expf(m - mn);
    float ps = 0.f;
#pragma unroll
    for (int nk = 0; nk < 4; ++nk)
#pragma unroll
      for (int j = 0; j < 4; ++j) {
        p[nk][j] = __expf(p[nk][j] - mn);
        ps += p[nk][j];
      }
    ps += __shfl_xor(ps, 16, 64);
    ps += __shfl_xor(ps, 32, 64);
    lsum = lsum * sc + ps;
    m = mn;
#pragma unroll
    for (int nd = 0; nd < 4; ++nd) {
      acc_o[nd][0] *= sc; acc_o[nd][1] *= sc;
      acc_o[nd][2] *= sc; acc_o[nd][3] *= sc;
    }

    unsigned int pk[4][2];
#pragma unroll
    for (int nk = 0; nk < 4; ++nk) {
      pk[nk][0] = (unsigned)f2bf(p[nk][0]) | ((unsigned)f2bf(p[nk][1]) << 16);
      pk[nk][1] = (unsigned)f2bf(p[nk][2]) | ((unsigned)f2bf(p[nk][3]) << 16);
    }

#pragma unroll
    for (int ks = 0; ks < 2; ++ks) {
      union { unsigned int d[4]; bf16x8 v; } pf;
      pf.d[0] = pk[ks][0];     pf.d[1] = pk[ks][1];
      pf.d[2] = pk[2 + ks][0]; pf.d[3] = pk[2 + ks][1];
#pragma unroll
      for (int nd = 0; nd < 4; ++nd) {
        int drow = nd * 16 + ln;
        int c16 = ks * 4 + g;
        bf16x8 vf = *(const bf16x8*)((const char*)Vs + drow * 128 +
                                     ((c16 ^ (drow & 7)) * 16));
        acc_o[nd] = __builtin_amdgcn_mfma_f32_16x16x32_bf16(vf, pf.v, acc_o[nd],
                                                            0, 0, 0);
      }
    }
  }

  float inv = 1.f / lsum;
  const int b_ = bh >> 4, h = bh & 15;
  unsigned short* op = ctx + ((size_t)b_ * T_DIM + q_abs) * D_DIM + h * DH_N;
#pragma unroll
  for (int nd = 0; nd < 4; ++nd) {
    u16x4 o;
#pragma unroll
    for (int j = 0; j < 4; ++j) o[j] = f2bf(acc_o[nd][j] * inv);
    *(u16x4*)(op + nd * 16 + g * 4) = o;
  }
}

// ---------------------------------------------------------------------------
extern "C" void kernel_launch(void* const* d_in, const int* in_sizes, int n_in,
                              void* d_out, int out_size, void* d_ws,
                              size_t ws_size, hipStream_t stream) {
  const float* x = (const float*)d_in[0];
  const float* w_qkv = (const float*)d_in[1];
  const float* b_qkv = (const float*)d_in[2];
  const float* w_out = (const float*)d_in[3];
  const float* b_out = (const float*)d_in[4];
  float* out = (float*)d_out;

  const size_t per = (size_t)BN * H_N * T_DIM * DH_N;  // 4,194,304
  unsigned short* qbf = (unsigned short*)d_ws;
  unsigned short* kbf = qbf + per;
  unsigned short* vtbf = kbf + per;                    // [B,H,64,T]
  unsigned short* xbf = vtbf + per;                    // [4096][1024]
  unsigned short* wqkvt = xbf + (size_t)NROWS * D_DIM; // [3072][1024]
  unsigned short* woutt = wqkvt + (size_t)3 * D_DIM * D_DIM;  // [1024][1024]
  unsigned short* ctxbf = woutt + (size_t)D_DIM * D_DIM;      // [4096][1024]

  convert_bf<<<dim3(NROWS * D_DIM / (256 * 8)), dim3(256), 0, stream>>>(x, xbf);
  convert_t<<<dim3(3 * D_DIM / 64, D_DIM / 64), dim3(256), 0, stream>>>(
      w_qkv, wqkvt, D_DIM, 3 * D_DIM);
  convert_t<<<dim3(D_DIM / 64, D_DIM / 64), dim3(256), 0, stream>>>(
      w_out, woutt, D_DIM, D_DIM);

  // qkv: grid = (3072/256)*(4096/256) = 12*16 = 192 blocks, 512 threads
  gemm256_qkv<<<dim3(192), dim3(512), 0, stream>>>(xbf, wqkvt, b_qkv, qbf, kbf,
                                                   vtbf);

  attn_mfma<<<dim3(BN * H_N * (T_DIM / 64)), dim3(256), 0, stream>>>(
      qbf, kbf, vtbf, ctxbf);

  mfma_gemm_out<<<dim3(D_DIM / 128, NROWS / 128), dim3(256), 0, stream>>>(
      ctxbf, woutt, b_out, out);
}

// Round 5
// 103.632 us; speedup vs baseline: 1.0432x; 1.0432x over previous
//
#include <hip/hip_runtime.h>

#define BN 2
#define T_DIM 2048
#define D_DIM 1024
#define H_N 16
#define DH_N 64
#define WIN 256
#define NROWS (BN * T_DIM)   // 4096
#define KDIM 1024            // inner dim for all GEMMs

typedef __attribute__((ext_vector_type(8))) short bf16x8;
typedef __attribute__((ext_vector_type(4))) float f32x4;
typedef __attribute__((ext_vector_type(8))) unsigned short ushort8;
typedef __attribute__((ext_vector_type(4))) unsigned short u16x4;

static __device__ __forceinline__ unsigned short f2bf(float f) {
  unsigned int u = __float_as_uint(f);
  unsigned int r = (u + 0x7FFFu + ((u >> 16) & 1u)) >> 16;  // RNE
  return (unsigned short)r;
}

static __device__ __forceinline__ void gl_lds16(const void* g, void* l) {
  __builtin_amdgcn_global_load_lds(
      (const __attribute__((address_space(1))) unsigned int*)g,
      (__attribute__((address_space(3))) unsigned int*)l, 16, 0, 0);
}

// ---------------------------------------------------------------------------
// f32 -> bf16 elementwise (8 elems/thread)
// ---------------------------------------------------------------------------
__global__ __launch_bounds__(256) void convert_bf(const float* __restrict__ src,
                                                  unsigned short* __restrict__ dst) {
  int i = (blockIdx.x * 256 + threadIdx.x) * 8;
  float4 a = *(const float4*)(src + i);
  float4 b = *(const float4*)(src + i + 4);
  ushort8 o;
  o[0] = f2bf(a.x); o[1] = f2bf(a.y); o[2] = f2bf(a.z); o[3] = f2bf(a.w);
  o[4] = f2bf(b.x); o[5] = f2bf(b.y); o[6] = f2bf(b.z); o[7] = f2bf(b.w);
  *(ushort8*)(dst + i) = o;
}

// ---------------------------------------------------------------------------
// f32 [R][C] -> bf16 [C][R] tiled transpose (64x64 tiles)
// ---------------------------------------------------------------------------
__global__ __launch_bounds__(256) void convert_t(const float* __restrict__ src,
                                                 unsigned short* __restrict__ dst,
                                                 int R, int C) {
  __shared__ float tile[64][65];
  const int t = threadIdx.x;
  const int bc = blockIdx.x * 64, br = blockIdx.y * 64;
#pragma unroll
  for (int i = 0; i < 16; ++i) {
    int idx = i * 256 + t;
    int r = idx >> 6, c = idx & 63;
    tile[r][c] = src[(size_t)(br + r) * C + bc + c];
  }
  __syncthreads();
#pragma unroll
  for (int i = 0; i < 16; ++i) {
    int idx = i * 256 + t;
    int r = idx >> 6, c = idx & 63;
    dst[(size_t)(bc + r) * R + br + c] = f2bf(tile[c][r]);
  }
}

// ---------------------------------------------------------------------------
// qkv GEMM, deep-pipelined: 256x192 tile -> grid 16x16 = 256 blocks (full CU
// fill). 8 waves (2M x 4N), per-wave 128x48. BK=32, QUAD-buffered LDS
// (112KB), prefetch lead = 3 K-tiles, counted vmcnt (12/9 per wave role),
// raw s_barrier, T5 setprio, T1 XCD swizzle.
// Epilogue: q,k bf16 [B,H,T,64] (q*0.125), v^T bf16 [B,H,64,T].
// ---------------------------------------------------------------------------
__global__ __launch_bounds__(512) void gemm_qkv_p4(
    const unsigned short* __restrict__ A, const unsigned short* __restrict__ Bt,
    const float* __restrict__ bias, unsigned short* __restrict__ qo,
    unsigned short* __restrict__ ko, unsigned short* __restrict__ vto) {
  __shared__ unsigned short As[4][8192];  // 4 bufs x 256 rows x 32 k = 64KB
  __shared__ unsigned short Bs[4][6144];  // 4 bufs x 192 rows x 32 k = 48KB

  const int tid = threadIdx.x;
  const int w = tid >> 6, l = tid & 63;
  const int wr = w >> 2, wc = w & 3;      // 2M x 4N; per-wave out 128x48
  const bool wlt4 = (w < 4);
  const int l15 = l & 15, kslc = l >> 4;

  // T1: XCD swizzle, nwg=256 (%8==0), M-major grouping per XCD
  const int id = blockIdx.x;
  const int wg = (id & 7) * 32 + (id >> 3);
  const int bx = wg & 15, by = wg >> 4;
  const int r0 = by * 256, c0 = bx * 192;

  const unsigned short* Ag = A + (size_t)r0 * KDIM;
  const unsigned short* Bg = Bt + (size_t)c0 * KDIM;

  f32x4 acc[8][3];
#pragma unroll
  for (int i = 0; i < 8; ++i)
#pragma unroll
    for (int j = 0; j < 3; ++j) acc[i][j] = (f32x4){0.f, 0.f, 0.f, 0.f};

  const int srow = l >> 2;                      // row-in-16 for staging
  const int srcslot = (l & 3) ^ (srow & 3);     // pre-swizzled global slot

#define STAGE_Q(T, BUF)                                                        \
  do {                                                                         \
    const size_t kk0 = (size_t)(T) * 32;                                       \
    gl_lds16(Ag + (size_t)(w * 16 + srow) * KDIM + kk0 + srcslot * 8,          \
             (char*)&As[BUF][0] + w * 1024);                                   \
    gl_lds16(Ag + (size_t)(128 + w * 16 + srow) * KDIM + kk0 + srcslot * 8,    \
             (char*)&As[BUF][0] + (8 + w) * 1024);                             \
    gl_lds16(Bg + (size_t)(w * 16 + srow) * KDIM + kk0 + srcslot * 8,          \
             (char*)&Bs[BUF][0] + w * 1024);                                   \
    if (wlt4)                                                                  \
      gl_lds16(Bg + (size_t)(128 + w * 16 + srow) * KDIM + kk0 + srcslot * 8,  \
               (char*)&Bs[BUF][0] + (8 + w) * 1024);                           \
  } while (0)

#define QCOMPUTE(CB)                                                           \
  do {                                                                         \
    bf16x8 af[4], bfr[3];                                                      \
    _Pragma("unroll") for (int mi = 0; mi < 4; ++mi) {                         \
      int row = wr * 128 + mi * 16 + l15;                                      \
      af[mi] = *(const bf16x8*)((const char*)&As[CB][0] + row * 64 +           \
                                ((kslc ^ (row & 3)) << 4));                    \
    }                                                                          \
    _Pragma("unroll") for (int ni = 0; ni < 3; ++ni) {                         \
      int row = wc * 48 + ni * 16 + l15;                                       \
      bfr[ni] = *(const bf16x8*)((const char*)&Bs[CB][0] + row * 64 +          \
                                 ((kslc ^ (row & 3)) << 4));                   \
    }                                                                          \
    __builtin_amdgcn_s_setprio(1);                                             \
    _Pragma("unroll") for (int mi = 0; mi < 4; ++mi)                           \
        _Pragma("unroll") for (int ni = 0; ni < 3; ++ni) acc[mi][ni] =         \
            __builtin_amdgcn_mfma_f32_16x16x32_bf16(af[mi], bfr[ni],           \
                                                    acc[mi][ni], 0, 0, 0);     \
    __builtin_amdgcn_s_setprio(0);                                             \
    _Pragma("unroll") for (int mi = 0; mi < 4; ++mi) {                         \
      int row = wr * 128 + (mi + 4) * 16 + l15;                                \
      af[mi] = *(const bf16x8*)((const char*)&As[CB][0] + row * 64 +           \
                                ((kslc ^ (row & 3)) << 4));                    \
    }                                                                          \
    __builtin_amdgcn_s_setprio(1);                                             \
    _Pragma("unroll") for (int mi = 0; mi < 4; ++mi)                           \
        _Pragma("unroll") for (int ni = 0; ni < 3; ++ni) acc[mi + 4][ni] =     \
            __builtin_amdgcn_mfma_f32_16x16x32_bf16(af[mi], bfr[ni],           \
                                                    acc[mi + 4][ni], 0, 0, 0); \
    __builtin_amdgcn_s_setprio(0);                                             \
  } while (0)

  // prologue: 3 tiles in flight
  STAGE_Q(0, 0);
  STAGE_Q(1, 1);
  STAGE_Q(2, 2);

  // steady state: lead-3, counted vmcnt (loads stay in flight across barriers)
  for (int t = 0; t < 29; ++t) {
    STAGE_Q(t + 3, (t + 3) & 3);
    if (wlt4) asm volatile("s_waitcnt vmcnt(12)" ::: "memory");
    else      asm volatile("s_waitcnt vmcnt(9)" ::: "memory");
    __builtin_amdgcn_s_barrier();      // tile t resident for all waves
    QCOMPUTE(t & 3);
    __builtin_amdgcn_s_barrier();      // reads of buf t&3 done -> reusable
  }
  // tail: drain 8/6 -> 4/3 -> 0
  if (wlt4) asm volatile("s_waitcnt vmcnt(8)" ::: "memory");
  else      asm volatile("s_waitcnt vmcnt(6)" ::: "memory");
  __builtin_amdgcn_s_barrier();
  QCOMPUTE(1);
  __builtin_amdgcn_s_barrier();
  if (wlt4) asm volatile("s_waitcnt vmcnt(4)" ::: "memory");
  else      asm volatile("s_waitcnt vmcnt(3)" ::: "memory");
  __builtin_amdgcn_s_barrier();
  QCOMPUTE(2);
  __builtin_amdgcn_s_barrier();
  asm volatile("s_waitcnt vmcnt(0)" ::: "memory");
  __builtin_amdgcn_s_barrier();
  QCOMPUTE(3);
#undef STAGE_Q
#undef QCOMPUTE

  // epilogue: per-fragment head decode (192-col tiles straddle q/k boundary)
#pragma unroll
  for (int ni = 0; ni < 3; ++ni) {
    const int col0 = c0 + wc * 48 + ni * 16;  // 16-aligned, within one head
    const int which = col0 >> 10;             // 0=q,1=k,2=v
    const int h = (col0 >> 6) & 15;
    const int dh = (col0 & 63) + l15;
    const float bv = bias[col0 + l15];
#pragma unroll
    for (int mi = 0; mi < 8; ++mi) {
      int row = r0 + wr * 128 + mi * 16 + (l >> 4) * 4;  // multiple of 4
      int b_ = row >> 11, t0 = row & 2047;
      if (which == 2) {
        u16x4 pk;
#pragma unroll
        for (int j = 0; j < 4; ++j) pk[j] = f2bf(acc[mi][ni][j] + bv);
        *(u16x4*)(vto + ((size_t)(b_ * H_N + h) * DH_N + dh) * T_DIM + t0) = pk;
      } else {
        float mul = (which == 0) ? 0.125f : 1.0f;
        unsigned short* dst = (which == 0) ? qo : ko;
#pragma unroll
        for (int j = 0; j < 4; ++j)
          dst[((size_t)(b_ * H_N + h) * T_DIM + t0 + j) * DH_N + dh] =
              f2bf((acc[mi][ni][j] + bv) * mul);
      }
    }
  }
}

// ---------------------------------------------------------------------------
// out-proj GEMM, deep-pipelined: 128x128 tile -> grid 32x8 = 256 blocks.
// 4 waves (2x2), per-wave 64x64, BK=32, quad-buffer (64KB), lead-3,
// counted vmcnt(12), raw s_barrier, setprio.  C = A@B + bias -> f32.
// ---------------------------------------------------------------------------
__global__ __launch_bounds__(256) void gemm_out_p4(
    const unsigned short* __restrict__ A, const unsigned short* __restrict__ Bt,
    const float* __restrict__ bias, float* __restrict__ fo) {
  __shared__ unsigned short As[4][4096];  // 4 bufs x 128 x 32 = 32KB
  __shared__ unsigned short Bs[4][4096];

  const int tid = threadIdx.x;
  const int w = tid >> 6, l = tid & 63;
  const int wr = w >> 1, wc = w & 1;
  const int l15 = l & 15, kslc = l >> 4;

  const int id = blockIdx.x;
  const int wg = (id & 7) * 32 + (id >> 3);
  const int bx = wg & 7, by = wg >> 3;
  const int r0 = by * 128, c0 = bx * 128;

  const unsigned short* Ag = A + (size_t)r0 * KDIM;
  const unsigned short* Bg = Bt + (size_t)c0 * KDIM;

  f32x4 acc[4][4];
#pragma unroll
  for (int i = 0; i < 4; ++i)
#pragma unroll
    for (int j = 0; j < 4; ++j) acc[i][j] = (f32x4){0.f, 0.f, 0.f, 0.f};

  const int srow = l >> 2;
  const int srcslot = (l & 3) ^ (srow & 3);

#define STAGE_O(T, BUF)                                                        \
  do {                                                                         \
    const size_t kk0 = (size_t)(T) * 32;                                       \
    gl_lds16(Ag + (size_t)(w * 16 + srow) * KDIM + kk0 + srcslot * 8,          \
             (char*)&As[BUF][0] + w * 1024);                                   \
    gl_lds16(Ag + (size_t)(64 + w * 16 + srow) * KDIM + kk0 + srcslot * 8,     \
             (char*)&As[BUF][0] + (4 + w) * 1024);                             \
    gl_lds16(Bg + (size_t)(w * 16 + srow) * KDIM + kk0 + srcslot * 8,          \
             (char*)&Bs[BUF][0] + w * 1024);                                   \
    gl_lds16(Bg + (size_t)(64 + w * 16 + srow) * KDIM + kk0 + srcslot * 8,     \
             (char*)&Bs[BUF][0] + (4 + w) * 1024);                             \
  } while (0)

#define OCOMPUTE(CB)                                                           \
  do {                                                                         \
    bf16x8 af[4], bfr[4];                                                      \
    _Pragma("unroll") for (int mi = 0; mi < 4; ++mi) {                         \
      int row = wr * 64 + mi * 16 + l15;                                       \
      af[mi] = *(const bf16x8*)((const char*)&As[CB][0] + row * 64 +           \
                                ((kslc ^ (row & 3)) << 4));                    \
    }                                                                          \
    _Pragma("unroll") for (int ni = 0; ni < 4; ++ni) {                         \
      int row = wc * 64 + ni * 16 + l15;                                       \
      bfr[ni] = *(const bf16x8*)((const char*)&Bs[CB][0] + row * 64 +          \
                                 ((kslc ^ (row & 3)) << 4));                   \
    }                                                                          \
    __builtin_amdgcn_s_setprio(1);                                             \
    _Pragma("unroll") for (int mi = 0; mi < 4; ++mi)                           \
        _Pragma("unroll") for (int ni = 0; ni < 4; ++ni) acc[mi][ni] =         \
            __builtin_amdgcn_mfma_f32_16x16x32_bf16(af[mi], bfr[ni],           \
                                                    acc[mi][ni], 0, 0, 0);     \
    __builtin_amdgcn_s_setprio(0);                                             \
  } while (0)

  STAGE_O(0, 0);
  STAGE_O(1, 1);
  STAGE_O(2, 2);

  for (int t = 0; t < 29; ++t) {
    STAGE_O(t + 3, (t + 3) & 3);
    asm volatile("s_waitcnt vmcnt(12)" ::: "memory");
    __builtin_amdgcn_s_barrier();
    OCOMPUTE(t & 3);
    __builtin_amdgcn_s_barrier();
  }
  asm volatile("s_waitcnt vmcnt(8)" ::: "memory");
  __builtin_amdgcn_s_barrier();
  OCOMPUTE(1);
  __builtin_amdgcn_s_barrier();
  asm volatile("s_waitcnt vmcnt(4)" ::: "memory");
  __builtin_amdgcn_s_barrier();
  OCOMPUTE(2);
  __builtin_amdgcn_s_barrier();
  asm volatile("s_waitcnt vmcnt(0)" ::: "memory");
  __builtin_amdgcn_s_barrier();
  OCOMPUTE(3);
#undef STAGE_O
#undef OCOMPUTE

#pragma unroll
  for (int mi = 0; mi < 4; ++mi) {
#pragma unroll
    for (int ni = 0; ni < 4; ++ni) {
      int row = r0 + wr * 64 + mi * 16 + (l >> 4) * 4;
      int col = c0 + wc * 64 + ni * 16 + l15;
      float bv = bias[col];
#pragma unroll
      for (int j = 0; j < 4; ++j)
        fo[(size_t)(row + j) * D_DIM + col] = acc[mi][ni][j] + bv;
    }
  }
}

// ---------------------------------------------------------------------------
// MFMA windowed flash attention (unchanged).
// ---------------------------------------------------------------------------
__global__ __launch_bounds__(256) void attn_mfma(
    const unsigned short* __restrict__ qbf,
    const unsigned short* __restrict__ kbf,
    const unsigned short* __restrict__ vtbf,
    unsigned short* __restrict__ ctx) {
  __shared__ unsigned short Ks[64 * 64];
  __shared__ unsigned short Vs[64 * 64];
  const int tid = threadIdx.x;
  const int w = tid >> 6, l = tid & 63;
  const int g = l >> 4, ln = l & 15;
  const int qt = blockIdx.x & 31;
  const int bh = blockIdx.x >> 5;
  const int q0 = qt * 64;
  const int q_abs = q0 + w * 16 + ln;

  const unsigned short* kp = kbf + (size_t)bh * T_DIM * DH_N;
  const unsigned short* vtp = vtbf + (size_t)bh * DH_N * T_DIM;

  bf16x8 qf0, qf1;
  {
    const unsigned short* qp = qbf + ((size_t)bh * T_DIM + q_abs) * DH_N;
    qf0 = *(const bf16x8*)(qp + g * 8);
    qf1 = *(const bf16x8*)(qp + 32 + g * 8);
  }

  f32x4 acc_o[4];
#pragma unroll
  for (int nd = 0; nd < 4; ++nd) acc_o[nd] = (f32x4){0.f, 0.f, 0.f, 0.f};
  float m = -1e30f, lsum = 0.f;

  const int kt_lo = (q0 >= WIN) ? (q0 - WIN) : 0;
  for (int kt = kt_lo; kt <= q0; kt += 64) {
    __syncthreads();
#pragma unroll
    for (int i = 0; i < 2; ++i) {
      int chunk = i * 256 + tid;
      int row = chunk >> 3, c16 = chunk & 7;
      int sc16 = c16 ^ (row & 7);
      int kap = 32 * ((row >> 4) & 1) + 8 * ((row & 15) >> 2) + 4 * (row >> 5) +
                (row & 3);
      gl_lds16(kp + (size_t)(kt + kap) * DH_N + sc16 * 8, (char*)Ks + chunk * 16);
      gl_lds16(vtp + (size_t)row * T_DIM + kt + sc16 * 8, (char*)Vs + chunk * 16);
    }
    __syncthreads();

    f32x4 sacc[4];
#pragma unroll
    for (int nk = 0; nk < 4; ++nk) sacc[nk] = (f32x4){0.f, 0.f, 0.f, 0.f};
#pragma unroll
    for (int ks = 0; ks < 2; ++ks) {
      bf16x8 qf = ks ? qf1 : qf0;
#pragma unroll
      for (int nk = 0; nk < 4; ++nk) {
        int rrow = nk * 16 + ln;
        int c16 = ks * 4 + g;
        bf16x8 kf = *(const bf16x8*)((const char*)Ks + rrow * 128 +
                                     ((c16 ^ (rrow & 7)) * 16));
        sacc[nk] = __builtin_amdgcn_mfma_f32_16x16x32_bf16(kf, qf, sacc[nk], 0, 0, 0);
      }
    }

    float p[4][4];
    float tm = -1e30f;
#pragma unroll
    for (int nk = 0; nk < 4; ++nk)
#pragma unroll
      for (int j = 0; j < 4; ++j) {
        int k_abs = kt + 32 * (nk & 1) + 8 * g + 4 * (nk >> 1) + j;
        float s = sacc[nk][j];
        bool ok = (k_abs <= q_abs) && (k_abs + WIN >= q_abs);
        s = ok ? s : -1e30f;
        p[nk][j] = s;
        tm = fmaxf(tm, s);
      }
    tm = fmaxf(tm, __shfl_xor(tm, 16, 64));
    tm = fmaxf(tm, __shfl_xor(tm, 32, 64));
    float mn = fmaxf(m, tm);
    float sc = __expf(m - mn);
    float ps = 0.f;
#pragma unroll
    for (int nk = 0; nk < 4; ++nk)
#pragma unroll
      for (int j = 0; j < 4; ++j) {
        p[nk][j] = __expf(p[nk][j] - mn);
        ps += p[nk][j];
      }
    ps += __shfl_xor(ps, 16, 64);
    ps += __shfl_xor(ps, 32, 64);
    lsum = lsum * sc + ps;
    m = mn;
#pragma unroll
    for (int nd = 0; nd < 4; ++nd) {
      acc_o[nd][0] *= sc; acc_o[nd][1] *= sc;
      acc_o[nd][2] *= sc; acc_o[nd][3] *= sc;
    }

    unsigned int pk[4][2];
#pragma unroll
    for (int nk = 0; nk < 4; ++nk) {
      pk[nk][0] = (unsigned)f2bf(p[nk][0]) | ((unsigned)f2bf(p[nk][1]) << 16);
      pk[nk][1] = (unsigned)f2bf(p[nk][2]) | ((unsigned)f2bf(p[nk][3]) << 16);
    }

#pragma unroll
    for (int ks = 0; ks < 2; ++ks) {
      union { unsigned int d[4]; bf16x8 v; } pf;
      pf.d[0] = pk[ks][0];     pf.d[1] = pk[ks][1];
      pf.d[2] = pk[2 + ks][0]; pf.d[3] = pk[2 + ks][1];
#pragma unroll
      for (int nd = 0; nd < 4; ++nd) {
        int drow = nd * 16 + ln;
        int c16 = ks * 4 + g;
        bf16x8 vf = *(const bf16x8*)((const char*)Vs + drow * 128 +
                                     ((c16 ^ (drow & 7)) * 16));
        acc_o[nd] = __builtin_amdgcn_mfma_f32_16x16x32_bf16(vf, pf.v, acc_o[nd],
                                                            0, 0, 0);
      }
    }
  }

  float inv = 1.f / lsum;
  const int b_ = bh >> 4, h = bh & 15;
  unsigned short* op = ctx + ((size_t)b_ * T_DIM + q_abs) * D_DIM + h * DH_N;
#pragma unroll
  for (int nd = 0; nd < 4; ++nd) {
    u16x4 o;
#pragma unroll
    for (int j = 0; j < 4; ++j) o[j] = f2bf(acc_o[nd][j] * inv);
    *(u16x4*)(op + nd * 16 + g * 4) = o;
  }
}

// ---------------------------------------------------------------------------
extern "C" void kernel_launch(void* const* d_in, const int* in_sizes, int n_in,
                              void* d_out, int out_size, void* d_ws,
                              size_t ws_size, hipStream_t stream) {
  const float* x = (const float*)d_in[0];
  const float* w_qkv = (const float*)d_in[1];
  const float* b_qkv = (const float*)d_in[2];
  const float* w_out = (const float*)d_in[3];
  const float* b_out = (const float*)d_in[4];
  float* out = (float*)d_out;

  const size_t per = (size_t)BN * H_N * T_DIM * DH_N;  // 4,194,304
  unsigned short* qbf = (unsigned short*)d_ws;
  unsigned short* kbf = qbf + per;
  unsigned short* vtbf = kbf + per;                    // [B,H,64,T]
  unsigned short* xbf = vtbf + per;                    // [4096][1024]
  unsigned short* wqkvt = xbf + (size_t)NROWS * D_DIM; // [3072][1024]
  unsigned short* woutt = wqkvt + (size_t)3 * D_DIM * D_DIM;  // [1024][1024]
  unsigned short* ctxbf = woutt + (size_t)D_DIM * D_DIM;      // [4096][1024]

  convert_bf<<<dim3(NROWS * D_DIM / (256 * 8)), dim3(256), 0, stream>>>(x, xbf);
  convert_t<<<dim3(3 * D_DIM / 64, D_DIM / 64), dim3(256), 0, stream>>>(
      w_qkv, wqkvt, D_DIM, 3 * D_DIM);
  convert_t<<<dim3(D_DIM / 64, D_DIM / 64), dim3(256), 0, stream>>>(
      w_out, woutt, D_DIM, D_DIM);

  // qkv: 256x192 tiles -> 16 x 16 = 256 blocks, 512 threads
  gemm_qkv_p4<<<dim3(256), dim3(512), 0, stream>>>(xbf, wqkvt, b_qkv, qbf, kbf,
                                                   vtbf);

  attn_mfma<<<dim3(BN * H_N * (T_DIM / 64)), dim3(256), 0, stream>>>(
      qbf, kbf, vtbf, ctxbf);

  // out-proj: 128x128 tiles -> 32 x 8 = 256 blocks, 256 threads
  gemm_out_p4<<<dim3(256), dim3(256), 0, stream>>>(ctxbf, woutt, b_out, out);
}

// Round 6
// 90.137 us; speedup vs baseline: 1.1994x; 1.1497x over previous
//
#include <hip/hip_runtime.h>

#define BN 2
#define T_DIM 2048
#define D_DIM 1024
#define H_N 16
#define DH_N 64
#define WIN 256
#define NROWS (BN * T_DIM)   // 4096
#define KDIM 1024            // inner dim for all GEMMs

typedef __attribute__((ext_vector_type(8))) short bf16x8;
typedef __attribute__((ext_vector_type(4))) float f32x4;
typedef __attribute__((ext_vector_type(8))) unsigned short ushort8;
typedef __attribute__((ext_vector_type(4))) unsigned short u16x4;

static __device__ __forceinline__ unsigned short f2bf(float f) {
  unsigned int u = __float_as_uint(f);
  unsigned int r = (u + 0x7FFFu + ((u >> 16) & 1u)) >> 16;  // RNE
  return (unsigned short)r;
}

static __device__ __forceinline__ void gl_lds16(const void* g, void* l) {
  __builtin_amdgcn_global_load_lds(
      (const __attribute__((address_space(1))) unsigned int*)g,
      (__attribute__((address_space(3))) unsigned int*)l, 16, 0, 0);
}

// ---------------------------------------------------------------------------
// f32 -> bf16 elementwise (8 elems/thread)
// ---------------------------------------------------------------------------
__global__ __launch_bounds__(256) void convert_bf(const float* __restrict__ src,
                                                  unsigned short* __restrict__ dst) {
  int i = (blockIdx.x * 256 + threadIdx.x) * 8;
  float4 a = *(const float4*)(src + i);
  float4 b = *(const float4*)(src + i + 4);
  ushort8 o;
  o[0] = f2bf(a.x); o[1] = f2bf(a.y); o[2] = f2bf(a.z); o[3] = f2bf(a.w);
  o[4] = f2bf(b.x); o[5] = f2bf(b.y); o[6] = f2bf(b.z); o[7] = f2bf(b.w);
  *(ushort8*)(dst + i) = o;
}

// ---------------------------------------------------------------------------
// f32 [R][C] -> bf16 [C][R] tiled transpose (64x64 tiles)
// ---------------------------------------------------------------------------
__global__ __launch_bounds__(256) void convert_t(const float* __restrict__ src,
                                                 unsigned short* __restrict__ dst,
                                                 int R, int C) {
  __shared__ float tile[64][65];
  const int t = threadIdx.x;
  const int bc = blockIdx.x * 64, br = blockIdx.y * 64;
#pragma unroll
  for (int i = 0; i < 16; ++i) {
    int idx = i * 256 + t;
    int r = idx >> 6, c = idx & 63;
    tile[r][c] = src[(size_t)(br + r) * C + bc + c];
  }
  __syncthreads();
#pragma unroll
  for (int i = 0; i < 16; ++i) {
    int idx = i * 256 + t;
    int r = idx >> 6, c = idx & 63;
    dst[(size_t)(bc + r) * R + br + c] = f2bf(tile[c][r]);
  }
}

// ---------------------------------------------------------------------------
// qkv GEMM: 256x192 tile, grid 16x16 = 256 blocks. 8 waves (2M x 4N),
// per-wave 128x48. BK=32, quad-buffered LDS (112KB), lead-2 prefetch,
// ONE barrier/iter (buffer-reuse distance 4 proves reads-done barrier
// removable), counted vmcnt (8/6), corrected bank swizzle
// slot = kslc ^ ((row>>1)&3)  (8 consecutive 64B rows -> 8 bank groups).
// Epilogue: q,k bf16 [B,H,T,64] (q*0.125), v^T bf16 [B,H,64,T].
// ---------------------------------------------------------------------------
__global__ __launch_bounds__(512) void gemm_qkv_p4(
    const unsigned short* __restrict__ A, const unsigned short* __restrict__ Bt,
    const float* __restrict__ bias, unsigned short* __restrict__ qo,
    unsigned short* __restrict__ ko, unsigned short* __restrict__ vto) {
  __shared__ unsigned short As[4][8192];  // 4 bufs x 256 rows x 32 k = 64KB
  __shared__ unsigned short Bs[4][6144];  // 4 bufs x 192 rows x 32 k = 48KB

  const int tid = threadIdx.x;
  const int w = tid >> 6, l = tid & 63;
  const int wr = w >> 2, wc = w & 3;      // 2M x 4N; per-wave out 128x48
  const bool wlt4 = (w < 4);
  const int l15 = l & 15, kslc = l >> 4;

  // T1: XCD swizzle, nwg=256 (%8==0)
  const int id = blockIdx.x;
  const int wg = (id & 7) * 32 + (id >> 3);
  const int bx = wg & 15, by = wg >> 4;
  const int r0 = by * 256, c0 = bx * 192;

  const unsigned short* Ag = A + (size_t)r0 * KDIM;
  const unsigned short* Bg = Bt + (size_t)c0 * KDIM;

  f32x4 acc[8][3];
#pragma unroll
  for (int i = 0; i < 8; ++i)
#pragma unroll
    for (int j = 0; j < 3; ++j) acc[i][j] = (f32x4){0.f, 0.f, 0.f, 0.f};

  const int srow = l >> 2;                          // row-in-16 for staging
  const int srcslot = (l & 3) ^ ((l >> 3) & 3);     // pre-swizzled global slot

#define STAGE_Q(T, BUF)                                                        \
  do {                                                                         \
    const size_t kk0 = (size_t)(T) * 32;                                       \
    gl_lds16(Ag + (size_t)(w * 16 + srow) * KDIM + kk0 + srcslot * 8,          \
             (char*)&As[BUF][0] + w * 1024);                                   \
    gl_lds16(Ag + (size_t)(128 + w * 16 + srow) * KDIM + kk0 + srcslot * 8,    \
             (char*)&As[BUF][0] + (8 + w) * 1024);                             \
    gl_lds16(Bg + (size_t)(w * 16 + srow) * KDIM + kk0 + srcslot * 8,          \
             (char*)&Bs[BUF][0] + w * 1024);                                   \
    if (wlt4)                                                                  \
      gl_lds16(Bg + (size_t)(128 + w * 16 + srow) * KDIM + kk0 + srcslot * 8,  \
               (char*)&Bs[BUF][0] + (8 + w) * 1024);                           \
  } while (0)

#define QCOMPUTE(CB)                                                           \
  do {                                                                         \
    bf16x8 af[4], bfr[3];                                                      \
    _Pragma("unroll") for (int mi = 0; mi < 4; ++mi) {                         \
      int row = wr * 128 + mi * 16 + l15;                                      \
      af[mi] = *(const bf16x8*)((const char*)&As[CB][0] + row * 64 +           \
                                ((kslc ^ ((row >> 1) & 3)) << 4));             \
    }                                                                          \
    _Pragma("unroll") for (int ni = 0; ni < 3; ++ni) {                         \
      int row = wc * 48 + ni * 16 + l15;                                       \
      bfr[ni] = *(const bf16x8*)((const char*)&Bs[CB][0] + row * 64 +          \
                                 ((kslc ^ ((row >> 1) & 3)) << 4));            \
    }                                                                          \
    __builtin_amdgcn_s_setprio(1);                                             \
    _Pragma("unroll") for (int mi = 0; mi < 4; ++mi)                           \
        _Pragma("unroll") for (int ni = 0; ni < 3; ++ni) acc[mi][ni] =         \
            __builtin_amdgcn_mfma_f32_16x16x32_bf16(af[mi], bfr[ni],           \
                                                    acc[mi][ni], 0, 0, 0);     \
    __builtin_amdgcn_s_setprio(0);                                             \
    _Pragma("unroll") for (int mi = 0; mi < 4; ++mi) {                         \
      int row = wr * 128 + (mi + 4) * 16 + l15;                                \
      af[mi] = *(const bf16x8*)((const char*)&As[CB][0] + row * 64 +           \
                                ((kslc ^ ((row >> 1) & 3)) << 4));             \
    }                                                                          \
    __builtin_amdgcn_s_setprio(1);                                             \
    _Pragma("unroll") for (int mi = 0; mi < 4; ++mi)                           \
        _Pragma("unroll") for (int ni = 0; ni < 3; ++ni) acc[mi + 4][ni] =     \
            __builtin_amdgcn_mfma_f32_16x16x32_bf16(af[mi], bfr[ni],           \
                                                    acc[mi + 4][ni], 0, 0, 0); \
    __builtin_amdgcn_s_setprio(0);                                             \
  } while (0)

  // prologue: 2 tiles in flight (lead-2)
  STAGE_Q(0, 0);
  STAGE_Q(1, 1);

  // steady state: one barrier per iteration; counted vmcnt before it
  for (int t = 0; t < 30; ++t) {
    STAGE_Q(t + 2, (t + 2) & 3);
    if (wlt4) asm volatile("s_waitcnt vmcnt(8)" ::: "memory");
    else      asm volatile("s_waitcnt vmcnt(6)" ::: "memory");
    __builtin_amdgcn_s_barrier();      // all waves' tile-t loads landed
    QCOMPUTE(t & 3);
  }
  // tail
  if (wlt4) asm volatile("s_waitcnt vmcnt(4)" ::: "memory");
  else      asm volatile("s_waitcnt vmcnt(3)" ::: "memory");
  __builtin_amdgcn_s_barrier();
  QCOMPUTE(2);
  asm volatile("s_waitcnt vmcnt(0)" ::: "memory");
  __builtin_amdgcn_s_barrier();
  QCOMPUTE(3);
#undef STAGE_Q
#undef QCOMPUTE

  // epilogue: per-fragment head decode
#pragma unroll
  for (int ni = 0; ni < 3; ++ni) {
    const int col0 = c0 + wc * 48 + ni * 16;  // 16-aligned, within one head
    const int which = col0 >> 10;             // 0=q,1=k,2=v
    const int h = (col0 >> 6) & 15;
    const int dh = (col0 & 63) + l15;
    const float bv = bias[col0 + l15];
#pragma unroll
    for (int mi = 0; mi < 8; ++mi) {
      int row = r0 + wr * 128 + mi * 16 + (l >> 4) * 4;  // multiple of 4
      int b_ = row >> 11, t0 = row & 2047;
      if (which == 2) {
        u16x4 pk;
#pragma unroll
        for (int j = 0; j < 4; ++j) pk[j] = f2bf(acc[mi][ni][j] + bv);
        *(u16x4*)(vto + ((size_t)(b_ * H_N + h) * DH_N + dh) * T_DIM + t0) = pk;
      } else {
        float mul = (which == 0) ? 0.125f : 1.0f;
        unsigned short* dst = (which == 0) ? qo : ko;
#pragma unroll
        for (int j = 0; j < 4; ++j)
          dst[((size_t)(b_ * H_N + h) * T_DIM + t0 + j) * DH_N + dh] =
              f2bf((acc[mi][ni][j] + bv) * mul);
      }
    }
  }
}

// ---------------------------------------------------------------------------
// out-proj GEMM: 128x128 tile, grid 32x8 = 256 blocks. 4 waves (2x2),
// per-wave 64x64, BK=32, quad-buffer (64KB), lead-2, one barrier/iter,
// counted vmcnt(8), corrected swizzle.  C = A@B + bias -> f32.
// ---------------------------------------------------------------------------
__global__ __launch_bounds__(256) void gemm_out_p4(
    const unsigned short* __restrict__ A, const unsigned short* __restrict__ Bt,
    const float* __restrict__ bias, float* __restrict__ fo) {
  __shared__ unsigned short As[4][4096];  // 4 bufs x 128 x 32 = 32KB
  __shared__ unsigned short Bs[4][4096];

  const int tid = threadIdx.x;
  const int w = tid >> 6, l = tid & 63;
  const int wr = w >> 1, wc = w & 1;
  const int l15 = l & 15, kslc = l >> 4;

  const int id = blockIdx.x;
  const int wg = (id & 7) * 32 + (id >> 3);
  const int bx = wg & 7, by = wg >> 3;
  const int r0 = by * 128, c0 = bx * 128;

  const unsigned short* Ag = A + (size_t)r0 * KDIM;
  const unsigned short* Bg = Bt + (size_t)c0 * KDIM;

  f32x4 acc[4][4];
#pragma unroll
  for (int i = 0; i < 4; ++i)
#pragma unroll
    for (int j = 0; j < 4; ++j) acc[i][j] = (f32x4){0.f, 0.f, 0.f, 0.f};

  const int srow = l >> 2;
  const int srcslot = (l & 3) ^ ((l >> 3) & 3);

#define STAGE_O(T, BUF)                                                        \
  do {                                                                         \
    const size_t kk0 = (size_t)(T) * 32;                                       \
    gl_lds16(Ag + (size_t)(w * 16 + srow) * KDIM + kk0 + srcslot * 8,          \
             (char*)&As[BUF][0] + w * 1024);                                   \
    gl_lds16(Ag + (size_t)(64 + w * 16 + srow) * KDIM + kk0 + srcslot * 8,     \
             (char*)&As[BUF][0] + (4 + w) * 1024);                             \
    gl_lds16(Bg + (size_t)(w * 16 + srow) * KDIM + kk0 + srcslot * 8,          \
             (char*)&Bs[BUF][0] + w * 1024);                                   \
    gl_lds16(Bg + (size_t)(64 + w * 16 + srow) * KDIM + kk0 + srcslot * 8,     \
             (char*)&Bs[BUF][0] + (4 + w) * 1024);                             \
  } while (0)

#define OCOMPUTE(CB)                                                           \
  do {                                                                         \
    bf16x8 af[4], bfr[4];                                                      \
    _Pragma("unroll") for (int mi = 0; mi < 4; ++mi) {                         \
      int row = wr * 64 + mi * 16 + l15;                                       \
      af[mi] = *(const bf16x8*)((const char*)&As[CB][0] + row * 64 +           \
                                ((kslc ^ ((row >> 1) & 3)) << 4));             \
    }                                                                          \
    _Pragma("unroll") for (int ni = 0; ni < 4; ++ni) {                         \
      int row = wc * 64 + ni * 16 + l15;                                       \
      bfr[ni] = *(const bf16x8*)((const char*)&Bs[CB][0] + row * 64 +          \
                                 ((kslc ^ ((row >> 1) & 3)) << 4));            \
    }                                                                          \
    __builtin_amdgcn_s_setprio(1);                                             \
    _Pragma("unroll") for (int mi = 0; mi < 4; ++mi)                           \
        _Pragma("unroll") for (int ni = 0; ni < 4; ++ni) acc[mi][ni] =         \
            __builtin_amdgcn_mfma_f32_16x16x32_bf16(af[mi], bfr[ni],           \
                                                    acc[mi][ni], 0, 0, 0);     \
    __builtin_amdgcn_s_setprio(0);                                             \
  } while (0)

  STAGE_O(0, 0);
  STAGE_O(1, 1);

  for (int t = 0; t < 30; ++t) {
    STAGE_O(t + 2, (t + 2) & 3);
    asm volatile("s_waitcnt vmcnt(8)" ::: "memory");
    __builtin_amdgcn_s_barrier();
    OCOMPUTE(t & 3);
  }
  asm volatile("s_waitcnt vmcnt(4)" ::: "memory");
  __builtin_amdgcn_s_barrier();
  OCOMPUTE(2);
  asm volatile("s_waitcnt vmcnt(0)" ::: "memory");
  __builtin_amdgcn_s_barrier();
  OCOMPUTE(3);
#undef STAGE_O
#undef OCOMPUTE

#pragma unroll
  for (int mi = 0; mi < 4; ++mi) {
#pragma unroll
    for (int ni = 0; ni < 4; ++ni) {
      int row = r0 + wr * 64 + mi * 16 + (l >> 4) * 4;
      int col = c0 + wc * 64 + ni * 16 + l15;
      float bv = bias[col];
#pragma unroll
      for (int j = 0; j < 4; ++j)
        fo[(size_t)(row + j) * D_DIM + col] = acc[mi][ni][j] + bv;
    }
  }
}

// ---------------------------------------------------------------------------
// MFMA windowed flash attention (unchanged).
// ---------------------------------------------------------------------------
__global__ __launch_bounds__(256) void attn_mfma(
    const unsigned short* __restrict__ qbf,
    const unsigned short* __restrict__ kbf,
    const unsigned short* __restrict__ vtbf,
    unsigned short* __restrict__ ctx) {
  __shared__ unsigned short Ks[64 * 64];
  __shared__ unsigned short Vs[64 * 64];
  const int tid = threadIdx.x;
  const int w = tid >> 6, l = tid & 63;
  const int g = l >> 4, ln = l & 15;
  const int qt = blockIdx.x & 31;
  const int bh = blockIdx.x >> 5;
  const int q0 = qt * 64;
  const int q_abs = q0 + w * 16 + ln;

  const unsigned short* kp = kbf + (size_t)bh * T_DIM * DH_N;
  const unsigned short* vtp = vtbf + (size_t)bh * DH_N * T_DIM;

  bf16x8 qf0, qf1;
  {
    const unsigned short* qp = qbf + ((size_t)bh * T_DIM + q_abs) * DH_N;
    qf0 = *(const bf16x8*)(qp + g * 8);
    qf1 = *(const bf16x8*)(qp + 32 + g * 8);
  }

  f32x4 acc_o[4];
#pragma unroll
  for (int nd = 0; nd < 4; ++nd) acc_o[nd] = (f32x4){0.f, 0.f, 0.f, 0.f};
  float m = -1e30f, lsum = 0.f;

  const int kt_lo = (q0 >= WIN) ? (q0 - WIN) : 0;
  for (int kt = kt_lo; kt <= q0; kt += 64) {
    __syncthreads();
#pragma unroll
    for (int i = 0; i < 2; ++i) {
      int chunk = i * 256 + tid;
      int row = chunk >> 3, c16 = chunk & 7;
      int sc16 = c16 ^ (row & 7);
      int kap = 32 * ((row >> 4) & 1) + 8 * ((row & 15) >> 2) + 4 * (row >> 5) +
                (row & 3);
      gl_lds16(kp + (size_t)(kt + kap) * DH_N + sc16 * 8, (char*)Ks + chunk * 16);
      gl_lds16(vtp + (size_t)row * T_DIM + kt + sc16 * 8, (char*)Vs + chunk * 16);
    }
    __syncthreads();

    f32x4 sacc[4];
#pragma unroll
    for (int nk = 0; nk < 4; ++nk) sacc[nk] = (f32x4){0.f, 0.f, 0.f, 0.f};
#pragma unroll
    for (int ks = 0; ks < 2; ++ks) {
      bf16x8 qf = ks ? qf1 : qf0;
#pragma unroll
      for (int nk = 0; nk < 4; ++nk) {
        int rrow = nk * 16 + ln;
        int c16 = ks * 4 + g;
        bf16x8 kf = *(const bf16x8*)((const char*)Ks + rrow * 128 +
                                     ((c16 ^ (rrow & 7)) * 16));
        sacc[nk] = __builtin_amdgcn_mfma_f32_16x16x32_bf16(kf, qf, sacc[nk], 0, 0, 0);
      }
    }

    float p[4][4];
    float tm = -1e30f;
#pragma unroll
    for (int nk = 0; nk < 4; ++nk)
#pragma unroll
      for (int j = 0; j < 4; ++j) {
        int k_abs = kt + 32 * (nk & 1) + 8 * g + 4 * (nk >> 1) + j;
        float s = sacc[nk][j];
        bool ok = (k_abs <= q_abs) && (k_abs + WIN >= q_abs);
        s = ok ? s : -1e30f;
        p[nk][j] = s;
        tm = fmaxf(tm, s);
      }
    tm = fmaxf(tm, __shfl_xor(tm, 16, 64));
    tm = fmaxf(tm, __shfl_xor(tm, 32, 64));
    float mn = fmaxf(m, tm);
    float sc = __expf(m - mn);
    float ps = 0.f;
#pragma unroll
    for (int nk = 0; nk < 4; ++nk)
#pragma unroll
      for (int j = 0; j < 4; ++j) {
        p[nk][j] = __expf(p[nk][j] - mn);
        ps += p[nk][j];
      }
    ps += __shfl_xor(ps, 16, 64);
    ps += __shfl_xor(ps, 32, 64);
    lsum = lsum * sc + ps;
    m = mn;
#pragma unroll
    for (int nd = 0; nd < 4; ++nd) {
      acc_o[nd][0] *= sc; acc_o[nd][1] *= sc;
      acc_o[nd][2] *= sc; acc_o[nd][3] *= sc;
    }

    unsigned int pk[4][2];
#pragma unroll
    for (int nk = 0; nk < 4; ++nk) {
      pk[nk][0] = (unsigned)f2bf(p[nk][0]) | ((unsigned)f2bf(p[nk][1]) << 16);
      pk[nk][1] = (unsigned)f2bf(p[nk][2]) | ((unsigned)f2bf(p[nk][3]) << 16);
    }

#pragma unroll
    for (int ks = 0; ks < 2; ++ks) {
      union { unsigned int d[4]; bf16x8 v; } pf;
      pf.d[0] = pk[ks][0];     pf.d[1] = pk[ks][1];
      pf.d[2] = pk[2 + ks][0]; pf.d[3] = pk[2 + ks][1];
#pragma unroll
      for (int nd = 0; nd < 4; ++nd) {
        int drow = nd * 16 + ln;
        int c16 = ks * 4 + g;
        bf16x8 vf = *(const bf16x8*)((const char*)Vs + drow * 128 +
                                     ((c16 ^ (drow & 7)) * 16));
        acc_o[nd] = __builtin_amdgcn_mfma_f32_16x16x32_bf16(vf, pf.v, acc_o[nd],
                                                            0, 0, 0);
      }
    }
  }

  float inv = 1.f / lsum;
  const int b_ = bh >> 4, h = bh & 15;
  unsigned short* op = ctx + ((size_t)b_ * T_DIM + q_abs) * D_DIM + h * DH_N;
#pragma unroll
  for (int nd = 0; nd < 4; ++nd) {
    u16x4 o;
#pragma unroll
    for (int j = 0; j < 4; ++j) o[j] = f2bf(acc_o[nd][j] * inv);
    *(u16x4*)(op + nd * 16 + g * 4) = o;
  }
}

// ---------------------------------------------------------------------------
extern "C" void kernel_launch(void* const* d_in, const int* in_sizes, int n_in,
                              void* d_out, int out_size, void* d_ws,
                              size_t ws_size, hipStream_t stream) {
  const float* x = (const float*)d_in[0];
  const float* w_qkv = (const float*)d_in[1];
  const float* b_qkv = (const float*)d_in[2];
  const float* w_out = (const float*)d_in[3];
  const float* b_out = (const float*)d_in[4];
  float* out = (float*)d_out;

  const size_t per = (size_t)BN * H_N * T_DIM * DH_N;  // 4,194,304
  unsigned short* qbf = (unsigned short*)d_ws;
  unsigned short* kbf = qbf + per;
  unsigned short* vtbf = kbf + per;                    // [B,H,64,T]
  unsigned short* xbf = vtbf + per;                    // [4096][1024]
  unsigned short* wqkvt = xbf + (size_t)NROWS * D_DIM; // [3072][1024]
  unsigned short* woutt = wqkvt + (size_t)3 * D_DIM * D_DIM;  // [1024][1024]
  unsigned short* ctxbf = woutt + (size_t)D_DIM * D_DIM;      // [4096][1024]

  convert_bf<<<dim3(NROWS * D_DIM / (256 * 8)), dim3(256), 0, stream>>>(x, xbf);
  convert_t<<<dim3(3 * D_DIM / 64, D_DIM / 64), dim3(256), 0, stream>>>(
      w_qkv, wqkvt, D_DIM, 3 * D_DIM);
  convert_t<<<dim3(D_DIM / 64, D_DIM / 64), dim3(256), 0, stream>>>(
      w_out, woutt, D_DIM, D_DIM);

  // qkv: 256x192 tiles -> 16 x 16 = 256 blocks, 512 threads
  gemm_qkv_p4<<<dim3(256), dim3(512), 0, stream>>>(xbf, wqkvt, b_qkv, qbf, kbf,
                                                   vtbf);

  attn_mfma<<<dim3(BN * H_N * (T_DIM / 64)), dim3(256), 0, stream>>>(
      qbf, kbf, vtbf, ctxbf);

  // out-proj: 128x128 tiles -> 32 x 8 = 256 blocks, 256 threads
  gemm_out_p4<<<dim3(256), dim3(256), 0, stream>>>(ctxbf, woutt, b_out, out);
}

// Round 7
// 90.067 us; speedup vs baseline: 1.2003x; 1.0008x over previous
//
#include <hip/hip_runtime.h>

#define BN 2
#define T_DIM 2048
#define D_DIM 1024
#define H_N 16
#define DH_N 64
#define WIN 256
#define NROWS (BN * T_DIM)   // 4096
#define KDIM 1024            // inner dim for all GEMMs

typedef __attribute__((ext_vector_type(8))) short bf16x8;
typedef __attribute__((ext_vector_type(4))) float f32x4;
typedef __attribute__((ext_vector_type(8))) unsigned short ushort8;
typedef __attribute__((ext_vector_type(4))) unsigned short u16x4;

static __device__ __forceinline__ unsigned short f2bf(float f) {
  unsigned int u = __float_as_uint(f);
  unsigned int r = (u + 0x7FFFu + ((u >> 16) & 1u)) >> 16;  // RNE
  return (unsigned short)r;
}

static __device__ __forceinline__ void gl_lds16(const void* g, void* l) {
  __builtin_amdgcn_global_load_lds(
      (const __attribute__((address_space(1))) unsigned int*)g,
      (__attribute__((address_space(3))) unsigned int*)l, 16, 0, 0);
}

// ---------------------------------------------------------------------------
// f32 -> bf16 elementwise (8 elems/thread)
// ---------------------------------------------------------------------------
__global__ __launch_bounds__(256) void convert_bf(const float* __restrict__ src,
                                                  unsigned short* __restrict__ dst) {
  int i = (blockIdx.x * 256 + threadIdx.x) * 8;
  float4 a = *(const float4*)(src + i);
  float4 b = *(const float4*)(src + i + 4);
  ushort8 o;
  o[0] = f2bf(a.x); o[1] = f2bf(a.y); o[2] = f2bf(a.z); o[3] = f2bf(a.w);
  o[4] = f2bf(b.x); o[5] = f2bf(b.y); o[6] = f2bf(b.z); o[7] = f2bf(b.w);
  *(ushort8*)(dst + i) = o;
}

// ---------------------------------------------------------------------------
// f32 [R][C] -> bf16 [C][R] tiled transpose (64x64 tiles)
// ---------------------------------------------------------------------------
__global__ __launch_bounds__(256) void convert_t(const float* __restrict__ src,
                                                 unsigned short* __restrict__ dst,
                                                 int R, int C) {
  __shared__ float tile[64][65];
  const int t = threadIdx.x;
  const int bc = blockIdx.x * 64, br = blockIdx.y * 64;
#pragma unroll
  for (int i = 0; i < 16; ++i) {
    int idx = i * 256 + t;
    int r = idx >> 6, c = idx & 63;
    tile[r][c] = src[(size_t)(br + r) * C + bc + c];
  }
  __syncthreads();
#pragma unroll
  for (int i = 0; i < 16; ++i) {
    int idx = i * 256 + t;
    int r = idx >> 6, c = idx & 63;
    dst[(size_t)(bc + r) * R + br + c] = f2bf(tile[c][r]);
  }
}

// ---------------------------------------------------------------------------
// qkv GEMM: 256x192 tile, grid 16x16 = 256 blocks. 8 waves (2M x 4N),
// per-wave 128x48. BK=32, quad-buffered LDS (112KB), lead-2 prefetch,
// ONE barrier/iter (buffer-reuse distance 4 proves reads-done barrier
// removable), counted vmcnt (8/6), corrected bank swizzle
// slot = kslc ^ ((row>>1)&3)  (8 consecutive 64B rows -> 8 bank groups).
// Epilogue: q,k bf16 [B,H,T,64] (q*0.125), v^T bf16 [B,H,64,T].
// ---------------------------------------------------------------------------
__global__ __launch_bounds__(512) void gemm_qkv_p4(
    const unsigned short* __restrict__ A, const unsigned short* __restrict__ Bt,
    const float* __restrict__ bias, unsigned short* __restrict__ qo,
    unsigned short* __restrict__ ko, unsigned short* __restrict__ vto) {
  __shared__ unsigned short As[4][8192];  // 4 bufs x 256 rows x 32 k = 64KB
  __shared__ unsigned short Bs[4][6144];  // 4 bufs x 192 rows x 32 k = 48KB

  const int tid = threadIdx.x;
  const int w = tid >> 6, l = tid & 63;
  const int wr = w >> 2, wc = w & 3;      // 2M x 4N; per-wave out 128x48
  const bool wlt4 = (w < 4);
  const int l15 = l & 15, kslc = l >> 4;

  // T1: XCD swizzle, nwg=256 (%8==0)
  const int id = blockIdx.x;
  const int wg = (id & 7) * 32 + (id >> 3);
  const int bx = wg & 15, by = wg >> 4;
  const int r0 = by * 256, c0 = bx * 192;

  const unsigned short* Ag = A + (size_t)r0 * KDIM;
  const unsigned short* Bg = Bt + (size_t)c0 * KDIM;

  f32x4 acc[8][3];
#pragma unroll
  for (int i = 0; i < 8; ++i)
#pragma unroll
    for (int j = 0; j < 3; ++j) acc[i][j] = (f32x4){0.f, 0.f, 0.f, 0.f};

  const int srow = l >> 2;                          // row-in-16 for staging
  const int srcslot = (l & 3) ^ ((l >> 3) & 3);     // pre-swizzled global slot

#define STAGE_Q(T, BUF)                                                        \
  do {                                                                         \
    const size_t kk0 = (size_t)(T) * 32;                                       \
    gl_lds16(Ag + (size_t)(w * 16 + srow) * KDIM + kk0 + srcslot * 8,          \
             (char*)&As[BUF][0] + w * 1024);                                   \
    gl_lds16(Ag + (size_t)(128 + w * 16 + srow) * KDIM + kk0 + srcslot * 8,    \
             (char*)&As[BUF][0] + (8 + w) * 1024);                             \
    gl_lds16(Bg + (size_t)(w * 16 + srow) * KDIM + kk0 + srcslot * 8,          \
             (char*)&Bs[BUF][0] + w * 1024);                                   \
    if (wlt4)                                                                  \
      gl_lds16(Bg + (size_t)(128 + w * 16 + srow) * KDIM + kk0 + srcslot * 8,  \
               (char*)&Bs[BUF][0] + (8 + w) * 1024);                           \
  } while (0)

#define QCOMPUTE(CB)                                                           \
  do {                                                                         \
    bf16x8 af[4], bfr[3];                                                      \
    _Pragma("unroll") for (int mi = 0; mi < 4; ++mi) {                         \
      int row = wr * 128 + mi * 16 + l15;                                      \
      af[mi] = *(const bf16x8*)((const char*)&As[CB][0] + row * 64 +           \
                                ((kslc ^ ((row >> 1) & 3)) << 4));             \
    }                                                                          \
    _Pragma("unroll") for (int ni = 0; ni < 3; ++ni) {                         \
      int row = wc * 48 + ni * 16 + l15;                                       \
      bfr[ni] = *(const bf16x8*)((const char*)&Bs[CB][0] + row * 64 +          \
                                 ((kslc ^ ((row >> 1) & 3)) << 4));            \
    }                                                                          \
    __builtin_amdgcn_s_setprio(1);                                             \
    _Pragma("unroll") for (int mi = 0; mi < 4; ++mi)                           \
        _Pragma("unroll") for (int ni = 0; ni < 3; ++ni) acc[mi][ni] =         \
            __builtin_amdgcn_mfma_f32_16x16x32_bf16(af[mi], bfr[ni],           \
                                                    acc[mi][ni], 0, 0, 0);     \
    __builtin_amdgcn_s_setprio(0);                                             \
    _Pragma("unroll") for (int mi = 0; mi < 4; ++mi) {                         \
      int row = wr * 128 + (mi + 4) * 16 + l15;                                \
      af[mi] = *(const bf16x8*)((const char*)&As[CB][0] + row * 64 +           \
                                ((kslc ^ ((row >> 1) & 3)) << 4));             \
    }                                                                          \
    __builtin_amdgcn_s_setprio(1);                                             \
    _Pragma("unroll") for (int mi = 0; mi < 4; ++mi)                           \
        _Pragma("unroll") for (int ni = 0; ni < 3; ++ni) acc[mi + 4][ni] =     \
            __builtin_amdgcn_mfma_f32_16x16x32_bf16(af[mi], bfr[ni],           \
                                                    acc[mi + 4][ni], 0, 0, 0); \
    __builtin_amdgcn_s_setprio(0);                                             \
  } while (0)

  // prologue: 2 tiles in flight (lead-2)
  STAGE_Q(0, 0);
  STAGE_Q(1, 1);

  // steady state: one barrier per iteration; counted vmcnt before it
  for (int t = 0; t < 30; ++t) {
    STAGE_Q(t + 2, (t + 2) & 3);
    if (wlt4) asm volatile("s_waitcnt vmcnt(8)" ::: "memory");
    else      asm volatile("s_waitcnt vmcnt(6)" ::: "memory");
    __builtin_amdgcn_s_barrier();      // all waves' tile-t loads landed
    QCOMPUTE(t & 3);
  }
  // tail
  if (wlt4) asm volatile("s_waitcnt vmcnt(4)" ::: "memory");
  else      asm volatile("s_waitcnt vmcnt(3)" ::: "memory");
  __builtin_amdgcn_s_barrier();
  QCOMPUTE(2);
  asm volatile("s_waitcnt vmcnt(0)" ::: "memory");
  __builtin_amdgcn_s_barrier();
  QCOMPUTE(3);
#undef STAGE_Q
#undef QCOMPUTE

  // epilogue: per-fragment head decode
#pragma unroll
  for (int ni = 0; ni < 3; ++ni) {
    const int col0 = c0 + wc * 48 + ni * 16;  // 16-aligned, within one head
    const int which = col0 >> 10;             // 0=q,1=k,2=v
    const int h = (col0 >> 6) & 15;
    const int dh = (col0 & 63) + l15;
    const float bv = bias[col0 + l15];
#pragma unroll
    for (int mi = 0; mi < 8; ++mi) {
      int row = r0 + wr * 128 + mi * 16 + (l >> 4) * 4;  // multiple of 4
      int b_ = row >> 11, t0 = row & 2047;
      if (which == 2) {
        u16x4 pk;
#pragma unroll
        for (int j = 0; j < 4; ++j) pk[j] = f2bf(acc[mi][ni][j] + bv);
        *(u16x4*)(vto + ((size_t)(b_ * H_N + h) * DH_N + dh) * T_DIM + t0) = pk;
      } else {
        float mul = (which == 0) ? 0.125f : 1.0f;
        unsigned short* dst = (which == 0) ? qo : ko;
#pragma unroll
        for (int j = 0; j < 4; ++j)
          dst[((size_t)(b_ * H_N + h) * T_DIM + t0 + j) * DH_N + dh] =
              f2bf((acc[mi][ni][j] + bv) * mul);
      }
    }
  }
}

// ---------------------------------------------------------------------------
// out-proj GEMM: 128x128 tile, grid 32x8 = 256 blocks. 4 waves (2x2),
// per-wave 64x64, BK=32, quad-buffer (64KB), lead-2, one barrier/iter,
// counted vmcnt(8), corrected swizzle.  C = A@B + bias -> f32.
// ---------------------------------------------------------------------------
__global__ __launch_bounds__(256) void gemm_out_p4(
    const unsigned short* __restrict__ A, const unsigned short* __restrict__ Bt,
    const float* __restrict__ bias, float* __restrict__ fo) {
  __shared__ unsigned short As[4][4096];  // 4 bufs x 128 x 32 = 32KB
  __shared__ unsigned short Bs[4][4096];

  const int tid = threadIdx.x;
  const int w = tid >> 6, l = tid & 63;
  const int wr = w >> 1, wc = w & 1;
  const int l15 = l & 15, kslc = l >> 4;

  const int id = blockIdx.x;
  const int wg = (id & 7) * 32 + (id >> 3);
  const int bx = wg & 7, by = wg >> 3;
  const int r0 = by * 128, c0 = bx * 128;

  const unsigned short* Ag = A + (size_t)r0 * KDIM;
  const unsigned short* Bg = Bt + (size_t)c0 * KDIM;

  f32x4 acc[4][4];
#pragma unroll
  for (int i = 0; i < 4; ++i)
#pragma unroll
    for (int j = 0; j < 4; ++j) acc[i][j] = (f32x4){0.f, 0.f, 0.f, 0.f};

  const int srow = l >> 2;
  const int srcslot = (l & 3) ^ ((l >> 3) & 3);

#define STAGE_O(T, BUF)                                                        \
  do {                                                                         \
    const size_t kk0 = (size_t)(T) * 32;                                       \
    gl_lds16(Ag + (size_t)(w * 16 + srow) * KDIM + kk0 + srcslot * 8,          \
             (char*)&As[BUF][0] + w * 1024);                                   \
    gl_lds16(Ag + (size_t)(64 + w * 16 + srow) * KDIM + kk0 + srcslot * 8,     \
             (char*)&As[BUF][0] + (4 + w) * 1024);                             \
    gl_lds16(Bg + (size_t)(w * 16 + srow) * KDIM + kk0 + srcslot * 8,          \
             (char*)&Bs[BUF][0] + w * 1024);                                   \
    gl_lds16(Bg + (size_t)(64 + w * 16 + srow) * KDIM + kk0 + srcslot * 8,     \
             (char*)&Bs[BUF][0] + (4 + w) * 1024);                             \
  } while (0)

#define OCOMPUTE(CB)                                                           \
  do {                                                                         \
    bf16x8 af[4], bfr[4];                                                      \
    _Pragma("unroll") for (int mi = 0; mi < 4; ++mi) {                         \
      int row = wr * 64 + mi * 16 + l15;                                       \
      af[mi] = *(const bf16x8*)((const char*)&As[CB][0] + row * 64 +           \
                                ((kslc ^ ((row >> 1) & 3)) << 4));             \
    }                                                                          \
    _Pragma("unroll") for (int ni = 0; ni < 4; ++ni) {                         \
      int row = wc * 64 + ni * 16 + l15;                                       \
      bfr[ni] = *(const bf16x8*)((const char*)&Bs[CB][0] + row * 64 +          \
                                 ((kslc ^ ((row >> 1) & 3)) << 4));            \
    }                                                                          \
    __builtin_amdgcn_s_setprio(1);                                             \
    _Pragma("unroll") for (int mi = 0; mi < 4; ++mi)                           \
        _Pragma("unroll") for (int ni = 0; ni < 4; ++ni) acc[mi][ni] =         \
            __builtin_amdgcn_mfma_f32_16x16x32_bf16(af[mi], bfr[ni],           \
                                                    acc[mi][ni], 0, 0, 0);     \
    __builtin_amdgcn_s_setprio(0);                                             \
  } while (0)

  STAGE_O(0, 0);
  STAGE_O(1, 1);

  for (int t = 0; t < 30; ++t) {
    STAGE_O(t + 2, (t + 2) & 3);
    asm volatile("s_waitcnt vmcnt(8)" ::: "memory");
    __builtin_amdgcn_s_barrier();
    OCOMPUTE(t & 3);
  }
  asm volatile("s_waitcnt vmcnt(4)" ::: "memory");
  __builtin_amdgcn_s_barrier();
  OCOMPUTE(2);
  asm volatile("s_waitcnt vmcnt(0)" ::: "memory");
  __builtin_amdgcn_s_barrier();
  OCOMPUTE(3);
#undef STAGE_O
#undef OCOMPUTE

#pragma unroll
  for (int mi = 0; mi < 4; ++mi) {
#pragma unroll
    for (int ni = 0; ni < 4; ++ni) {
      int row = r0 + wr * 64 + mi * 16 + (l >> 4) * 4;
      int col = c0 + wc * 64 + ni * 16 + l15;
      float bv = bias[col];
#pragma unroll
      for (int j = 0; j < 4; ++j)
        fo[(size_t)(row + j) * D_DIM + col] = acc[mi][ni][j] + bv;
    }
  }
}

// ---------------------------------------------------------------------------
// MFMA windowed flash attention (unchanged).
// ---------------------------------------------------------------------------
__global__ __launch_bounds__(256) void attn_mfma(
    const unsigned short* __restrict__ qbf,
    const unsigned short* __restrict__ kbf,
    const unsigned short* __restrict__ vtbf,
    unsigned short* __restrict__ ctx) {
  __shared__ unsigned short Ks[64 * 64];
  __shared__ unsigned short Vs[64 * 64];
  const int tid = threadIdx.x;
  const int w = tid >> 6, l = tid & 63;
  const int g = l >> 4, ln = l & 15;
  const int qt = blockIdx.x & 31;
  const int bh = blockIdx.x >> 5;
  const int q0 = qt * 64;
  const int q_abs = q0 + w * 16 + ln;

  const unsigned short* kp = kbf + (size_t)bh * T_DIM * DH_N;
  const unsigned short* vtp = vtbf + (size_t)bh * DH_N * T_DIM;

  bf16x8 qf0, qf1;
  {
    const unsigned short* qp = qbf + ((size_t)bh * T_DIM + q_abs) * DH_N;
    qf0 = *(const bf16x8*)(qp + g * 8);
    qf1 = *(const bf16x8*)(qp + 32 + g * 8);
  }

  f32x4 acc_o[4];
#pragma unroll
  for (int nd = 0; nd < 4; ++nd) acc_o[nd] = (f32x4){0.f, 0.f, 0.f, 0.f};
  float m = -1e30f, lsum = 0.f;

  const int kt_lo = (q0 >= WIN) ? (q0 - WIN) : 0;
  for (int kt = kt_lo; kt <= q0; kt += 64) {
    __syncthreads();
#pragma unroll
    for (int i = 0; i < 2; ++i) {
      int chunk = i * 256 + tid;
      int row = chunk >> 3, c16 = chunk & 7;
      int sc16 = c16 ^ (row & 7);
      int kap = 32 * ((row >> 4) & 1) + 8 * ((row & 15) >> 2) + 4 * (row >> 5) +
                (row & 3);
      gl_lds16(kp + (size_t)(kt + kap) * DH_N + sc16 * 8, (char*)Ks + chunk * 16);
      gl_lds16(vtp + (size_t)row * T_DIM + kt + sc16 * 8, (char*)Vs + chunk * 16);
    }
    __syncthreads();

    f32x4 sacc[4];
#pragma unroll
    for (int nk = 0; nk < 4; ++nk) sacc[nk] = (f32x4){0.f, 0.f, 0.f, 0.f};
#pragma unroll
    for (int ks = 0; ks < 2; ++ks) {
      bf16x8 qf = ks ? qf1 : qf0;
#pragma unroll
      for (int nk = 0; nk < 4; ++nk) {
        int rrow = nk * 16 + ln;
        int c16 = ks * 4 + g;
        bf16x8 kf = *(const bf16x8*)((const char*)Ks + rrow * 128 +
                                     ((c16 ^ (rrow & 7)) * 16));
        sacc[nk] = __builtin_amdgcn_mfma_f32_16x16x32_bf16(kf, qf, sacc[nk], 0, 0, 0);
      }
    }

    float p[4][4];
    float tm = -1e30f;
#pragma unroll
    for (int nk = 0; nk < 4; ++nk)
#pragma unroll
      for (int j = 0; j < 4; ++j) {
        int k_abs = kt + 32 * (nk & 1) + 8 * g + 4 * (nk >> 1) + j;
        float s = sacc[nk][j];
        bool ok = (k_abs <= q_abs) && (k_abs + WIN >= q_abs);
        s = ok ? s : -1e30f;
        p[nk][j] = s;
        tm = fmaxf(tm, s);
      }
    tm = fmaxf(tm, __shfl_xor(tm, 16, 64));
    tm = fmaxf(tm, __shfl_xor(tm, 32, 64));
    float mn = fmaxf(m, tm);
    float sc = __expf(m - mn);
    float ps = 0.f;
#pragma unroll
    for (int nk = 0; nk < 4; ++nk)
#pragma unroll
      for (int j = 0; j < 4; ++j) {
        p[nk][j] = __expf(p[nk][j] - mn);
        ps += p[nk][j];
      }
    ps += __shfl_xor(ps, 16, 64);
    ps += __shfl_xor(ps, 32, 64);
    lsum = lsum * sc + ps;
    m = mn;
#pragma unroll
    for (int nd = 0; nd < 4; ++nd) {
      acc_o[nd][0] *= sc; acc_o[nd][1] *= sc;
      acc_o[nd][2] *= sc; acc_o[nd][3] *= sc;
    }

    unsigned int pk[4][2];
#pragma unroll
    for (int nk = 0; nk < 4; ++nk) {
      pk[nk][0] = (unsigned)f2bf(p[nk][0]) | ((unsigned)f2bf(p[nk][1]) << 16);
      pk[nk][1] = (unsigned)f2bf(p[nk][2]) | ((unsigned)f2bf(p[nk][3]) << 16);
    }

#pragma unroll
    for (int ks = 0; ks < 2; ++ks) {
      union { unsigned int d[4]; bf16x8 v; } pf;
      pf.d[0] = pk[ks][0];     pf.d[1] = pk[ks][1];
      pf.d[2] = pk[2 + ks][0]; pf.d[3] = pk[2 + ks][1];
#pragma unroll
      for (int nd = 0; nd < 4; ++nd) {
        int drow = nd * 16 + ln;
        int c16 = ks * 4 + g;
        bf16x8 vf = *(const bf16x8*)((const char*)Vs + drow * 128 +
                                     ((c16 ^ (drow & 7)) * 16));
        acc_o[nd] = __builtin_amdgcn_mfma_f32_16x16x32_bf16(vf, pf.v, acc_o[nd],
                                                            0, 0, 0);
      }
    }
  }

  float inv = 1.f / lsum;
  const int b_ = bh >> 4, h = bh & 15;
  unsigned short* op = ctx + ((size_t)b_ * T_DIM + q_abs) * D_DIM + h * DH_N;
#pragma unroll
  for (int nd = 0; nd < 4; ++nd) {
    u16x4 o;
#pragma unroll
    for (int j = 0; j < 4; ++j) o[j] = f2bf(acc_o[nd][j] * inv);
    *(u16x4*)(op + nd * 16 + g * 4) = o;
  }
}

// ---------------------------------------------------------------------------
extern "C" void kernel_launch(void* const* d_in, const int* in_sizes, int n_in,
                              void* d_out, int out_size, void* d_ws,
                              size_t ws_size, hipStream_t stream) {
  const float* x = (const float*)d_in[0];
  const float* w_qkv = (const float*)d_in[1];
  const float* b_qkv = (const float*)d_in[2];
  const float* w_out = (const float*)d_in[3];
  const float* b_out = (const float*)d_in[4];
  float* out = (float*)d_out;

  const size_t per = (size_t)BN * H_N * T_DIM * DH_N;  // 4,194,304
  unsigned short* qbf = (unsigned short*)d_ws;
  unsigned short* kbf = qbf + per;
  unsigned short* vtbf = kbf + per;                    // [B,H,64,T]
  unsigned short* xbf = vtbf + per;                    // [4096][1024]
  unsigned short* wqkvt = xbf + (size_t)NROWS * D_DIM; // [3072][1024]
  unsigned short* woutt = wqkvt + (size_t)3 * D_DIM * D_DIM;  // [1024][1024]
  unsigned short* ctxbf = woutt + (size_t)D_DIM * D_DIM;      // [4096][1024]

  convert_bf<<<dim3(NROWS * D_DIM / (256 * 8)), dim3(256), 0, stream>>>(x, xbf);
  convert_t<<<dim3(3 * D_DIM / 64, D_DIM / 64), dim3(256), 0, stream>>>(
      w_qkv, wqkvt, D_DIM, 3 * D_DIM);
  convert_t<<<dim3(D_DIM / 64, D_DIM / 64), dim3(256), 0, stream>>>(
      w_out, woutt, D_DIM, D_DIM);

  // qkv: 256x192 tiles -> 16 x 16 = 256 blocks, 512 threads
  gemm_qkv_p4<<<dim3(256), dim3(512), 0, stream>>>(xbf, wqkvt, b_qkv, qbf, kbf,
                                                   vtbf);

  attn_mfma<<<dim3(BN * H_N * (T_DIM / 64)), dim3(256), 0, stream>>>(
      qbf, kbf, vtbf, ctxbf);

  // out-proj: 128x128 tiles -> 32 x 8 = 256 blocks, 256 threads
  gemm_out_p4<<<dim3(256), dim3(256), 0, stream>>>(ctxbf, woutt, b_out, out);
}